// Round 23
// baseline (390.649 us; speedup 1.0000x reference)
//
#include <hip/hip_runtime.h>
#include <hip/hip_bf16.h>

typedef unsigned short u16;
typedef unsigned int u32;
typedef unsigned long long u64;
typedef __attribute__((ext_vector_type(8))) short short8;
typedef __attribute__((ext_vector_type(4))) float floatx4;

#define MFMA16(a,b,c) __builtin_amdgcn_mfma_f32_16x16x32_bf16((a),(b),(c),0,0,0)

__device__ __forceinline__ u16 f2bf(float f){
  u32 x = __float_as_uint(f);
  x += 0x7FFFu + ((x >> 16) & 1u);
  return (u16)(x >> 16);
}
__device__ __forceinline__ float frcp(float x){ return __builtin_amdgcn_rcpf(x); }
__device__ __forceinline__ float fexp2(float x){ return __builtin_amdgcn_exp2f(x); }
// 0.125 * log2(e): scale folded into the exp2 argument
#define KEXP 0.18033688011112042f
#define Z4 ((floatx4){0.f,0.f,0.f,0.f})

// async global->LDS 16B per lane: LDS dest = wave-uniform base + lane*16,
// global src is per-lane (pre-swizzled source pattern).
__device__ __forceinline__ void gl_lds16(const u16* src, u16* dst){
  __builtin_amdgcn_global_load_lds(
      (const __attribute__((address_space(1))) unsigned int*)(u64)(src),
      (__attribute__((address_space(3))) unsigned int*)(u32)(u64)(dst),
      16, 0, 0);
}

// ---------------- x f32 -> bf16 one-shot convert (streaming, R22-proven) -------------
__global__ __launch_bounds__(256) void k_xcvt(
    const float* __restrict__ xq, const float* __restrict__ xk, const float* __restrict__ xv,
    u16* __restrict__ xb)
{
  const int z = blockIdx.y;
  const float* x = (z == 0) ? xq : ((z == 1) ? xk : xv);
  const size_t i = ((size_t)blockIdx.x * 256 + threadIdx.x) * 8;   // < 8388608
  float4 f0 = *(const float4*)(x + i), f1 = *(const float4*)(x + i + 4);
  short8 v;
  v[0] = (short)f2bf(f0.x); v[1] = (short)f2bf(f0.y);
  v[2] = (short)f2bf(f0.z); v[3] = (short)f2bf(f0.w);
  v[4] = (short)f2bf(f1.x); v[5] = (short)f2bf(f1.y);
  v[6] = (short)f2bf(f1.z); v[7] = (short)f2bf(f1.w);
  *(short8*)(xb + (size_t)z * 8388608 + i) = v;
}

// ---------------- weight transpose+convert via LDS tiles (R19-proven) ----------------
__global__ __launch_bounds__(256) void k_wt6(
    const float* __restrict__ w0, const float* __restrict__ w1, const float* __restrict__ w2,
    const float* __restrict__ w3, const float* __restrict__ w4, const float* __restrict__ w5,
    u16* __restrict__ wts)
{
  __shared__ u16 T[64][66];
  const int z = blockIdx.z;
  const float* w;
  switch (z){ case 0: w = w0; break; case 1: w = w1; break; case 2: w = w2; break;
              case 3: w = w3; break; case 4: w = w4; break; default: w = w5; break; }
  const int j0 = blockIdx.x * 64, d0 = blockIdx.y * 64;
  const int c = threadIdx.x & 63, r = threadIdx.x >> 6;
  #pragma unroll
  for (int it = 0; it < 16; ++it){
    const int rr = it * 4 + r;
    T[c][rr] = f2bf(w[(size_t)(d0 + rr) * 512 + j0 + c]);
  }
  __syncthreads();
  u16* out = wts + (size_t)z * 262144;
  #pragma unroll
  for (int it = 0; it < 16; ++it){
    const int jr = it * 4 + r;
    out[(size_t)(j0 + jr) * 512 + d0 + c] = T[jr][c];
  }
}

// ---------------- 5-way projection GEMM v2 (R22-proven): both operands via gl_lds16 --
__global__ __launch_bounds__(256) void k_proj(
    const u16* __restrict__ xb, const u16* __restrict__ wts,
    const float* __restrict__ bq, const float* __restrict__ bk, const float* __restrict__ bv,
    const float* __restrict__ bq1, const float* __restrict__ bk1,
    u16* __restrict__ Qh, u16* __restrict__ Kh, u16* __restrict__ Vt,
    u16* __restrict__ Q1h, u16* __restrict__ K1h)
{
  __shared__ __align__(16) u16 Asf[128 * 64];
  __shared__ __align__(16) u16 Bsf[128 * 64];
  const int z = blockIdx.z;
  const int xsel = (z == 3) ? 0 : ((z == 4) ? 1 : z);
  const u16* x = xb + (size_t)xsel * 8388608;
  const float* bias; u16* out; int vtm = 0;
  switch (z){
    case 0: bias = bq;  out = Qh;  break;
    case 1: bias = bk;  out = Kh;  break;
    case 2: bias = bv;  out = Vt;  vtm = 1; break;
    case 3: bias = bq1; out = Q1h; break;
    default: bias = bk1; out = K1h; break;
  }
  const u16* wt = wts + (size_t)z * 262144;
  const int tid = threadIdx.x, lane = tid & 63, wid = tid >> 6;
  const int wm = wid >> 1, wn = wid & 1;
  const int m0 = blockIdx.x * 128, n0 = blockIdx.y * 128;
  const int arow = lane & 15, kg = lane >> 4;
  const int br = tid >> 3, bc = tid & 7;
  u16* const adst = Asf + wid * 512;
  u16* const bdst = Bsf + wid * 512;

  floatx4 acc[4][4];
  #pragma unroll
  for (int i = 0; i < 4; ++i)
    #pragma unroll
    for (int j = 0; j < 4; ++j) acc[i][j] = Z4;

  for (int k0 = 0; k0 < 512; k0 += 64){
    #pragma unroll
    for (int q = 0; q < 4; ++q){
      gl_lds16(x  + (size_t)(m0 + q * 32 + br) * 512 + k0 + ((bc ^ (br & 7)) * 8),
               adst + q * 2048);
      gl_lds16(wt + (size_t)(n0 + q * 32 + br) * 512 + k0 + ((bc ^ (br & 7)) * 8),
               bdst + q * 2048);
    }
    __syncthreads();
    #pragma unroll
    for (int kk = 0; kk < 2; ++kk){
      short8 af[4], bf[4];
      #pragma unroll
      for (int mm = 0; mm < 4; ++mm){
        int rr = wm * 64 + mm * 16 + arow;
        af[mm] = *(const short8*)&Asf[rr * 64 + ((kk * 32 + kg * 8) ^ ((rr & 7) * 8))];
      }
      #pragma unroll
      for (int nn = 0; nn < 4; ++nn){
        int rr = wn * 64 + nn * 16 + arow;
        bf[nn] = *(const short8*)&Bsf[rr * 64 + ((kk * 32 + kg * 8) ^ ((rr & 7) * 8))];
      }
      #pragma unroll
      for (int mm = 0; mm < 4; ++mm)
        #pragma unroll
        for (int nn = 0; nn < 4; ++nn)
          acc[mm][nn] = MFMA16(af[mm], bf[nn], acc[mm][nn]);
    }
    __syncthreads();
  }
  #pragma unroll
  for (int mm = 0; mm < 4; ++mm)
    #pragma unroll
    for (int nn = 0; nn < 4; ++nn){
      int j = n0 + wn * 64 + nn * 16 + arow;
      int h = j >> 6, dh = j & 63;
      float bval = bias[j];
      #pragma unroll
      for (int i = 0; i < 4; ++i){
        int sg = m0 + wm * 64 + mm * 16 + kg * 4 + i;
        int bb = sg >> 10, s = sg & 1023;
        float val = acc[mm][nn][i] + bval;
        size_t o = vtm ? (((size_t)((bb << 3) + h) * 64 + dh) * 1024 + s)
                       : (((size_t)((bb << 3) + h) * 1024 + s) * 64 + dh);
        out[o] = f2bf(val);
      }
    }
}

// ================= SPLIT PATH =================
// ---------------- kernel A (R17-proven): k-outer / q-inner dual-QK -> U, rsum --------
__global__ void __launch_bounds__(1024)
k_qk(const u16* __restrict__ Qh, const u16* __restrict__ Kh,
     const u16* __restrict__ Q1h, const u16* __restrict__ K1h,
     const int* __restrict__ mask, u16* __restrict__ U, float* __restrict__ rsum)
{
  __shared__ __align__(16) u16 stg[2 * 8192];

  const int tid = threadIdx.x, lane = tid & 63, wid = tid >> 6;
  const int arow = lane & 15, kg = lane >> 4;
  const int b = blockIdx.x, h = blockIdx.y, qs = blockIdx.z;
  const size_t hb = (size_t)(b * 8 + h);

  const int qrow = qs * 256 + wid * 16 + arow;
  const u16* qp  = Qh  + (hb * 1024 + qrow) * 64 + kg * 8;
  const u16* q1p = Q1h + (hb * 1024 + qrow) * 64 + kg * 8;
  short8 aq0 = *(const short8*)qp,  aq1 = *(const short8*)(qp + 32);
  short8 ap0 = *(const short8*)q1p, ap1 = *(const short8*)(q1p + 32);

  u64 mb = 0;
  #pragma unroll
  for (int t = 0; t < 16; ++t)
    #pragma unroll
    for (int cs = 0; cs < 4; ++cs)
      mb |= (mask[b * 1024 + t * 64 + cs * 16 + arow] != 0 ? 1ull : 0ull) << (t * 4 + cs);

  const int ls_half = tid >> 9;
  const int ls_r = (tid & 511) >> 3;
  const int ls_c = (tid & 7) ^ (ls_r & 7);
  u16* const sbase = stg + wid * 512;
  const u16* lsrc = (ls_half ? Kh : K1h) + hb * 65536 + (size_t)ls_r * 64 + ls_c * 8;

  u16* const ubase = U + hb * 1048576;
  const int urow0 = qs * 256 + wid * 16 + kg * 4;

  gl_lds16(lsrc, sbase);
  __syncthreads();

  float sacc[4] = {0.f, 0.f, 0.f, 0.f};
  for (int t = 0; t < 16; ++t){
    if (t < 15)
      gl_lds16(lsrc + (size_t)(t + 1) * 4096, sbase + (((t + 1) & 1) << 13));
    const u16* kb = stg + ((t & 1) << 13);
    #pragma unroll
    for (int cs = 0; cs < 4; ++cs){
      const int krow = cs * 16 + arow;
      const int swl = (krow & 7) * 8;
      short8 b1a = *(const short8*)&kb[krow * 64 + ((     kg * 8) ^ swl)];
      short8 b1b = *(const short8*)&kb[krow * 64 + ((32 + kg * 8) ^ swl)];
      short8 bea = *(const short8*)&kb[4096 + krow * 64 + ((     kg * 8) ^ swl)];
      short8 beb = *(const short8*)&kb[4096 + krow * 64 + ((32 + kg * 8) ^ swl)];
      floatx4 cg4 = Z4, ce4 = Z4;
      cg4 = MFMA16(ap0, b1a, cg4); cg4 = MFMA16(ap1, b1b, cg4);
      ce4 = MFMA16(aq0, bea, ce4); ce4 = MFMA16(aq1, beb, ce4);
      const float msk = ((mb >> (t * 4 + cs)) & 1ull) ? 1.0f : 0.0f;
      #pragma unroll
      for (int i = 0; i < 4; ++i){
        float p = fexp2(ce4[i] * KEXP) * msk;
        float g = frcp(1.0f + fexp2(-cg4[i] * KEXP));
        sacc[i] += p;
        ubase[(size_t)(urow0 + i) * 1024 + t * 64 + cs * 16 + arow] = f2bf(p * g);
      }
    }
    __syncthreads();
  }

  #pragma unroll
  for (int i = 0; i < 4; ++i){
    #pragma unroll
    for (int off = 1; off <= 8; off <<= 1)
      sacc[i] += __shfl_xor(sacc[i], off, 64);
  }
  if (arow == 0){
    #pragma unroll
    for (int i = 0; i < 4; ++i)
      rsum[hb * 1024 + urow0 + i] = sacc[i];
  }
}

// ---------------- kernel B v5: U staged, V DIRECT from global (L2-hot) ---------------
// grid (16 b, 16 qt of 64 rows); 1024 thr (16 waves); LDS 32 KB (dbuf x U 16KB).
// V[h] (128 KB) is re-read by all 16 qt blocks -> L2-resident; per-lane 16B with 64B
// kg-contiguity. Halves per-tile DMA issues (2 -> 1 per thread) — the duty-cycle
// pacing item (R10: ~5250 cyc/tile vs ~3200 transfer). Unlike R7/R15, only ONE
// operand is demand-loaded and racc VALU + A ds_reads + 16-wave TLP cover it.
__global__ void __launch_bounds__(1024)
__attribute__((amdgpu_waves_per_eu(4, 4)))
k_pvr(const u16* __restrict__ U, const float* __restrict__ rsum,
      const u16* __restrict__ Vt, u16* __restrict__ xa, float* __restrict__ ratt)
{
  extern __shared__ __align__(16) u16 stg2[];   // 2 bufs x 8192 u16 (U tiles)

  const int tid = threadIdx.x, lane = tid & 63, wid = tid >> 6;
  const int arow = lane & 15, kg = lane >> 4;
  const int b = blockIdx.x, qt = blockIdx.y;
  const int rs = wid & 3, cs2 = wid >> 2;
  const int cres = cs2 * 16 + arow;
  const int wrow = wid * 4;
  const int a_r = rs * 16 + arow;

  const int ur = tid >> 4, uc = (tid & 15) ^ (ur & 7);

  float racc[4][16];
  #pragma unroll
  for (int r = 0; r < 4; ++r)
    #pragma unroll
    for (int j = 0; j < 16; ++j) racc[r][j] = 0.f;

  for (int h = 0; h < 8; ++h){
    const size_t hb = (size_t)(b * 8 + h);
    const u16* ub = U  + hb * 1048576 + (size_t)(qt * 64) * 1024;
    const u16* vp = Vt + hb * 65536 + (size_t)cres * 1024 + kg * 8;   // per-lane V base

    float rlh[4], rlx[4];
    #pragma unroll
    for (int r = 0; r < 4; ++r)
      rlh[r] = frcp(rsum[hb * 1024 + qt * 64 + wrow + r]) * 0.125f;
    #pragma unroll
    for (int i = 0; i < 4; ++i)
      rlx[i] = frcp(rsum[hb * 1024 + qt * 64 + rs * 16 + kg * 4 + i]);

    gl_lds16(ub + (size_t)ur * 1024 + uc * 8, stg2 + tid * 8);
    __syncthreads();

    floatx4 cpv = Z4;
    for (int t = 0; t < 8; ++t){
      if (t < 7)
        gl_lds16(ub + (size_t)ur * 1024 + (t + 1) * 128 + uc * 8,
                 stg2 + (((t + 1) & 1) << 13) + tid * 8);
      const u16* Ut = stg2 + ((t & 1) << 13);
      // racc from staged U
      #pragma unroll
      for (int r = 0; r < 4; ++r){
        const int row = wrow + r;
        u32 w = *(const u32*)&Ut[row * 128 + ((lane * 2) ^ ((row & 7) * 8))];
        racc[r][2 * t]     += __uint_as_float(w << 16) * rlh[r];
        racc[r][2 * t + 1] += __uint_as_float(w & 0xFFFF0000u) * rlh[r];
      }
      // PV MFMA: A from staged U, B direct from global V (L2-hot)
      #pragma unroll
      for (int ks = 0; ks < 4; ++ks){
        short8 a  = *(const short8*)&Ut[a_r * 128 + ((ks * 32 + kg * 8) ^ ((a_r & 7) * 8))];
        short8 bv = *(const short8*)(vp + t * 128 + ks * 32);
        cpv = MFMA16(a, bv, cpv);
      }
      __syncthreads();
    }
    #pragma unroll
    for (int i = 0; i < 4; ++i){
      const int g = qt * 64 + rs * 16 + kg * 4 + i;
      xa[((size_t)(b * 1024 + g)) * 512 + h * 64 + cres] = f2bf(cpv[i] * rlx[i]);
    }
  }

  #pragma unroll
  for (int r = 0; r < 4; ++r){
    const size_t rb = ((size_t)(b * 1024 + qt * 64 + wrow + r)) * 1024;
    #pragma unroll
    for (int j = 0; j < 8; ++j){
      float2 v = {racc[r][2 * j], racc[r][2 * j + 1]};
      *(float2*)&ratt[rb + j * 128 + lane * 2] = v;
    }
  }
}

// ---------------- final FC, 128x128 tile (R14-proven) ----------------
__global__ __launch_bounds__(256) void k_fc(
    const u16* __restrict__ xa, const u16* __restrict__ wt,
    const float* __restrict__ bias, float* __restrict__ out)
{
  __shared__ __align__(16) u16 Asf[128 * 64];
  __shared__ __align__(16) u16 Bsf[128 * 64];
  const int tid = threadIdx.x, lane = tid & 63, wid = tid >> 6;
  const int wm = wid >> 1, wn = wid & 1;
  const int m0 = blockIdx.x * 128, n0 = blockIdx.y * 128;
  const int arow = lane & 15, kg = lane >> 4;
  const int br = tid >> 3, bc = tid & 7;
  u16* const adst = Asf + wid * 512;
  u16* const bdst = Bsf + wid * 512;

  floatx4 acc[4][4];
  #pragma unroll
  for (int i = 0; i < 4; ++i)
    #pragma unroll
    for (int j = 0; j < 4; ++j) acc[i][j] = Z4;

  for (int k0 = 0; k0 < 512; k0 += 64){
    #pragma unroll
    for (int q = 0; q < 4; ++q){
      gl_lds16(xa + (size_t)(m0 + q * 32 + br) * 512 + k0 + ((bc ^ (br & 7)) * 8),
               adst + q * 2048);
      gl_lds16(wt + (size_t)(n0 + q * 32 + br) * 512 + k0 + ((bc ^ (br & 7)) * 8),
               bdst + q * 2048);
    }
    __syncthreads();
    #pragma unroll
    for (int kk = 0; kk < 2; ++kk){
      short8 af[4], bf[4];
      #pragma unroll
      for (int mm = 0; mm < 4; ++mm){
        int rr = wm * 64 + mm * 16 + arow;
        af[mm] = *(const short8*)&Asf[rr * 64 + ((kk * 32 + kg * 8) ^ ((rr & 7) * 8))];
      }
      #pragma unroll
      for (int nn = 0; nn < 4; ++nn){
        int rr = wn * 64 + nn * 16 + arow;
        bf[nn] = *(const short8*)&Bsf[rr * 64 + ((kk * 32 + kg * 8) ^ ((rr & 7) * 8))];
      }
      #pragma unroll
      for (int mm = 0; mm < 4; ++mm)
        #pragma unroll
        for (int nn = 0; nn < 4; ++nn)
          acc[mm][nn] = MFMA16(af[mm], bf[nn], acc[mm][nn]);
    }
    __syncthreads();
  }
  #pragma unroll
  for (int mm = 0; mm < 4; ++mm)
    #pragma unroll
    for (int nn = 0; nn < 4; ++nn){
      int j = n0 + wn * 64 + nn * 16 + arow;
      float bval = bias[j];
      #pragma unroll
      for (int i = 0; i < 4; ++i){
        int sg = m0 + wm * 64 + mm * 16 + kg * 4 + i;
        out[(size_t)sg * 512 + j] = acc[mm][nn][i] + bval;
      }
    }
}

extern "C" void kernel_launch(void* const* d_in, const int* in_sizes, int n_in,
                              void* d_out, int out_size, void* d_ws, size_t ws_size,
                              hipStream_t stream)
{
  const float* query = (const float*)d_in[0];
  const float* key   = (const float*)d_in[1];
  const float* value = (const float*)d_in[2];
  const int*   mask  = (const int*)d_in[3];
  const float* wq  = (const float*)d_in[4];  const float* bq  = (const float*)d_in[5];
  const float* wk  = (const float*)d_in[6];  const float* bk  = (const float*)d_in[7];
  const float* wv  = (const float*)d_in[8];  const float* bv  = (const float*)d_in[9];
  const float* wq1 = (const float*)d_in[10]; const float* bq1 = (const float*)d_in[11];
  const float* wk1 = (const float*)d_in[12]; const float* bk1 = (const float*)d_in[13];
  const float* wfc = (const float*)d_in[14]; const float* bfc = (const float*)d_in[15];

  u16* ws  = (u16*)d_ws;
  u16* Qh  = ws;
  u16* Kh  = Qh  + 8388608;
  u16* Vt  = Kh  + 8388608;
  u16* Q1h = Vt  + 8388608;
  u16* K1h = Q1h + 8388608;
  u16* xa  = K1h + 8388608;
  u16* wts = xa  + 8388608;           // 6 * 262144 u16
  u16* U   = wts + 6 * 262144;        // 134217728 u16 = 268 MB
  float* rsum = (float*)(U + 134217728);  // 131072 f32
  u16* xb  = U;                       // bf16 x (3 x 8388608 u16 = 50 MB), aliased over
                                      // U: written by k_xcvt, read by k_proj, dead
                                      // before k_qk writes U.

  float* outx = (float*)d_out;
  float* ratt = outx + 8388608;

  k_wt6<<<dim3(8, 8, 6), dim3(256), 0, stream>>>(wq, wk, wv, wq1, wk1, wfc, wts);

  k_xcvt<<<dim3(4096, 3), dim3(256), 0, stream>>>(query, key, value, xb);

  k_proj<<<dim3(128, 4, 5), dim3(256), 0, stream>>>(
      xb, wts, bq, bk, bv, bq1, bk1, Qh, Kh, Vt, Q1h, K1h);

  (void)hipFuncSetAttribute((const void*)k_pvr,
                            hipFuncAttributeMaxDynamicSharedMemorySize, 32768);
  k_qk<<<dim3(16, 8, 4), dim3(1024), 0, stream>>>(
      Qh, Kh, Q1h, K1h, mask, U, rsum);
  k_pvr<<<dim3(16, 16), dim3(1024), 32768, stream>>>(
      U, rsum, Vt, xa, ratt);

  k_fc<<<dim3(128, 4), dim3(256), 0, stream>>>(
      xa, wts + 5 * 262144, bfc, outx);
}

// Round 24
// 355.730 us; speedup vs baseline: 1.0982x; 1.0982x over previous
//
#include <hip/hip_runtime.h>
#include <hip/hip_bf16.h>

typedef unsigned short u16;
typedef unsigned int u32;
typedef unsigned long long u64;
typedef __attribute__((ext_vector_type(8))) short short8;
typedef __attribute__((ext_vector_type(4))) float floatx4;

#define MFMA16(a,b,c) __builtin_amdgcn_mfma_f32_16x16x32_bf16((a),(b),(c),0,0,0)

__device__ __forceinline__ u16 f2bf(float f){
  u32 x = __float_as_uint(f);
  x += 0x7FFFu + ((x >> 16) & 1u);
  return (u16)(x >> 16);
}
__device__ __forceinline__ float frcp(float x){ return __builtin_amdgcn_rcpf(x); }
__device__ __forceinline__ float fexp2(float x){ return __builtin_amdgcn_exp2f(x); }
// 0.125 * log2(e): scale folded into the exp2 argument
#define KEXP 0.18033688011112042f
#define Z4 ((floatx4){0.f,0.f,0.f,0.f})

// async global->LDS 16B per lane: LDS dest = wave-uniform base + lane*16,
// global src is per-lane (pre-swizzled source pattern).
__device__ __forceinline__ void gl_lds16(const u16* src, u16* dst){
  __builtin_amdgcn_global_load_lds(
      (const __attribute__((address_space(1))) unsigned int*)(u64)(src),
      (__attribute__((address_space(3))) unsigned int*)(u32)(u64)(dst),
      16, 0, 0);
}

// ---------------- x f32 -> bf16 one-shot convert (streaming, R22-proven) -------------
__global__ __launch_bounds__(256) void k_xcvt(
    const float* __restrict__ xq, const float* __restrict__ xk, const float* __restrict__ xv,
    u16* __restrict__ xb)
{
  const int z = blockIdx.y;
  const float* x = (z == 0) ? xq : ((z == 1) ? xk : xv);
  const size_t i = ((size_t)blockIdx.x * 256 + threadIdx.x) * 8;   // < 8388608
  float4 f0 = *(const float4*)(x + i), f1 = *(const float4*)(x + i + 4);
  short8 v;
  v[0] = (short)f2bf(f0.x); v[1] = (short)f2bf(f0.y);
  v[2] = (short)f2bf(f0.z); v[3] = (short)f2bf(f0.w);
  v[4] = (short)f2bf(f1.x); v[5] = (short)f2bf(f1.y);
  v[6] = (short)f2bf(f1.z); v[7] = (short)f2bf(f1.w);
  *(short8*)(xb + (size_t)z * 8388608 + i) = v;
}

// ---------------- weight transpose+convert via LDS tiles (R19-proven) ----------------
__global__ __launch_bounds__(256) void k_wt6(
    const float* __restrict__ w0, const float* __restrict__ w1, const float* __restrict__ w2,
    const float* __restrict__ w3, const float* __restrict__ w4, const float* __restrict__ w5,
    u16* __restrict__ wts)
{
  __shared__ u16 T[64][66];
  const int z = blockIdx.z;
  const float* w;
  switch (z){ case 0: w = w0; break; case 1: w = w1; break; case 2: w = w2; break;
              case 3: w = w3; break; case 4: w = w4; break; default: w = w5; break; }
  const int j0 = blockIdx.x * 64, d0 = blockIdx.y * 64;
  const int c = threadIdx.x & 63, r = threadIdx.x >> 6;
  #pragma unroll
  for (int it = 0; it < 16; ++it){
    const int rr = it * 4 + r;
    T[c][rr] = f2bf(w[(size_t)(d0 + rr) * 512 + j0 + c]);
  }
  __syncthreads();
  u16* out = wts + (size_t)z * 262144;
  #pragma unroll
  for (int it = 0; it < 16; ++it){
    const int jr = it * 4 + r;
    out[(size_t)(j0 + jr) * 512 + d0 + c] = T[jr][c];
  }
}

// ---------------- 5-way projection GEMM v2 (R22-proven): both operands via gl_lds16 --
__global__ __launch_bounds__(256) void k_proj(
    const u16* __restrict__ xb, const u16* __restrict__ wts,
    const float* __restrict__ bq, const float* __restrict__ bk, const float* __restrict__ bv,
    const float* __restrict__ bq1, const float* __restrict__ bk1,
    u16* __restrict__ Qh, u16* __restrict__ Kh, u16* __restrict__ Vt,
    u16* __restrict__ Q1h, u16* __restrict__ K1h)
{
  __shared__ __align__(16) u16 Asf[128 * 64];
  __shared__ __align__(16) u16 Bsf[128 * 64];
  const int z = blockIdx.z;
  const int xsel = (z == 3) ? 0 : ((z == 4) ? 1 : z);
  const u16* x = xb + (size_t)xsel * 8388608;
  const float* bias; u16* out; int vtm = 0;
  switch (z){
    case 0: bias = bq;  out = Qh;  break;
    case 1: bias = bk;  out = Kh;  break;
    case 2: bias = bv;  out = Vt;  vtm = 1; break;
    case 3: bias = bq1; out = Q1h; break;
    default: bias = bk1; out = K1h; break;
  }
  const u16* wt = wts + (size_t)z * 262144;
  const int tid = threadIdx.x, lane = tid & 63, wid = tid >> 6;
  const int wm = wid >> 1, wn = wid & 1;
  const int m0 = blockIdx.x * 128, n0 = blockIdx.y * 128;
  const int arow = lane & 15, kg = lane >> 4;
  const int br = tid >> 3, bc = tid & 7;
  u16* const adst = Asf + wid * 512;
  u16* const bdst = Bsf + wid * 512;

  floatx4 acc[4][4];
  #pragma unroll
  for (int i = 0; i < 4; ++i)
    #pragma unroll
    for (int j = 0; j < 4; ++j) acc[i][j] = Z4;

  for (int k0 = 0; k0 < 512; k0 += 64){
    #pragma unroll
    for (int q = 0; q < 4; ++q){
      gl_lds16(x  + (size_t)(m0 + q * 32 + br) * 512 + k0 + ((bc ^ (br & 7)) * 8),
               adst + q * 2048);
      gl_lds16(wt + (size_t)(n0 + q * 32 + br) * 512 + k0 + ((bc ^ (br & 7)) * 8),
               bdst + q * 2048);
    }
    __syncthreads();
    #pragma unroll
    for (int kk = 0; kk < 2; ++kk){
      short8 af[4], bf[4];
      #pragma unroll
      for (int mm = 0; mm < 4; ++mm){
        int rr = wm * 64 + mm * 16 + arow;
        af[mm] = *(const short8*)&Asf[rr * 64 + ((kk * 32 + kg * 8) ^ ((rr & 7) * 8))];
      }
      #pragma unroll
      for (int nn = 0; nn < 4; ++nn){
        int rr = wn * 64 + nn * 16 + arow;
        bf[nn] = *(const short8*)&Bsf[rr * 64 + ((kk * 32 + kg * 8) ^ ((rr & 7) * 8))];
      }
      #pragma unroll
      for (int mm = 0; mm < 4; ++mm)
        #pragma unroll
        for (int nn = 0; nn < 4; ++nn)
          acc[mm][nn] = MFMA16(af[mm], bf[nn], acc[mm][nn]);
    }
    __syncthreads();
  }
  #pragma unroll
  for (int mm = 0; mm < 4; ++mm)
    #pragma unroll
    for (int nn = 0; nn < 4; ++nn){
      int j = n0 + wn * 64 + nn * 16 + arow;
      int h = j >> 6, dh = j & 63;
      float bval = bias[j];
      #pragma unroll
      for (int i = 0; i < 4; ++i){
        int sg = m0 + wm * 64 + mm * 16 + kg * 4 + i;
        int bb = sg >> 10, s = sg & 1023;
        float val = acc[mm][nn][i] + bval;
        size_t o = vtm ? (((size_t)((bb << 3) + h) * 64 + dh) * 1024 + s)
                       : (((size_t)((bb << 3) + h) * 1024 + s) * 64 + dh);
        out[o] = f2bf(val);
      }
    }
}

// ================= SPLIT PATH =================
// ---------------- kernel A (R17-proven): k-outer / q-inner dual-QK -> U, rsum --------
__global__ void __launch_bounds__(1024)
k_qk(const u16* __restrict__ Qh, const u16* __restrict__ Kh,
     const u16* __restrict__ Q1h, const u16* __restrict__ K1h,
     const int* __restrict__ mask, u16* __restrict__ U, float* __restrict__ rsum)
{
  __shared__ __align__(16) u16 stg[2 * 8192];

  const int tid = threadIdx.x, lane = tid & 63, wid = tid >> 6;
  const int arow = lane & 15, kg = lane >> 4;
  const int b = blockIdx.x, h = blockIdx.y, qs = blockIdx.z;
  const size_t hb = (size_t)(b * 8 + h);

  const int qrow = qs * 256 + wid * 16 + arow;
  const u16* qp  = Qh  + (hb * 1024 + qrow) * 64 + kg * 8;
  const u16* q1p = Q1h + (hb * 1024 + qrow) * 64 + kg * 8;
  short8 aq0 = *(const short8*)qp,  aq1 = *(const short8*)(qp + 32);
  short8 ap0 = *(const short8*)q1p, ap1 = *(const short8*)(q1p + 32);

  u64 mb = 0;
  #pragma unroll
  for (int t = 0; t < 16; ++t)
    #pragma unroll
    for (int cs = 0; cs < 4; ++cs)
      mb |= (mask[b * 1024 + t * 64 + cs * 16 + arow] != 0 ? 1ull : 0ull) << (t * 4 + cs);

  const int ls_half = tid >> 9;
  const int ls_r = (tid & 511) >> 3;
  const int ls_c = (tid & 7) ^ (ls_r & 7);
  u16* const sbase = stg + wid * 512;
  const u16* lsrc = (ls_half ? Kh : K1h) + hb * 65536 + (size_t)ls_r * 64 + ls_c * 8;

  u16* const ubase = U + hb * 1048576;
  const int urow0 = qs * 256 + wid * 16 + kg * 4;

  gl_lds16(lsrc, sbase);
  __syncthreads();

  float sacc[4] = {0.f, 0.f, 0.f, 0.f};
  for (int t = 0; t < 16; ++t){
    if (t < 15)
      gl_lds16(lsrc + (size_t)(t + 1) * 4096, sbase + (((t + 1) & 1) << 13));
    const u16* kb = stg + ((t & 1) << 13);
    #pragma unroll
    for (int cs = 0; cs < 4; ++cs){
      const int krow = cs * 16 + arow;
      const int swl = (krow & 7) * 8;
      short8 b1a = *(const short8*)&kb[krow * 64 + ((     kg * 8) ^ swl)];
      short8 b1b = *(const short8*)&kb[krow * 64 + ((32 + kg * 8) ^ swl)];
      short8 bea = *(const short8*)&kb[4096 + krow * 64 + ((     kg * 8) ^ swl)];
      short8 beb = *(const short8*)&kb[4096 + krow * 64 + ((32 + kg * 8) ^ swl)];
      floatx4 cg4 = Z4, ce4 = Z4;
      cg4 = MFMA16(ap0, b1a, cg4); cg4 = MFMA16(ap1, b1b, cg4);
      ce4 = MFMA16(aq0, bea, ce4); ce4 = MFMA16(aq1, beb, ce4);
      const float msk = ((mb >> (t * 4 + cs)) & 1ull) ? 1.0f : 0.0f;
      #pragma unroll
      for (int i = 0; i < 4; ++i){
        float p = fexp2(ce4[i] * KEXP) * msk;
        float g = frcp(1.0f + fexp2(-cg4[i] * KEXP));
        sacc[i] += p;
        ubase[(size_t)(urow0 + i) * 1024 + t * 64 + cs * 16 + arow] = f2bf(p * g);
      }
    }
    __syncthreads();
  }

  #pragma unroll
  for (int i = 0; i < 4; ++i){
    #pragma unroll
    for (int off = 1; off <= 8; off <<= 1)
      sacc[i] += __shfl_xor(sacc[i], off, 64);
  }
  if (arow == 0){
    #pragma unroll
    for (int i = 0; i < 4; ++i)
      rsum[hb * 1024 + urow0 + i] = sacc[i];
  }
}

// ---------------- kernel B v4 (R20/R22-proven): 64-row blocks, U+V staged ------------
__global__ void __launch_bounds__(1024)
__attribute__((amdgpu_waves_per_eu(4, 4)))
k_pvr(const u16* __restrict__ U, const float* __restrict__ rsum,
      const u16* __restrict__ Vt, u16* __restrict__ xa, float* __restrict__ ratt)
{
  extern __shared__ __align__(16) u16 stg2[];   // 2 bufs x 16384 u16: U[0,8192) V[8192,16384)

  const int tid = threadIdx.x, lane = tid & 63, wid = tid >> 6;
  const int arow = lane & 15, kg = lane >> 4;
  const int b = blockIdx.x, qt = blockIdx.y;
  const int rs = wid & 3, cs2 = wid >> 2;
  const int cres = cs2 * 16 + arow;
  const int wrow = wid * 4;
  const int a_r = rs * 16 + arow;

  const int ur = tid >> 4, uc = (tid & 15) ^ (ur & 7);

  float racc[4][16];
  #pragma unroll
  for (int r = 0; r < 4; ++r)
    #pragma unroll
    for (int j = 0; j < 16; ++j) racc[r][j] = 0.f;

  for (int h = 0; h < 8; ++h){
    const size_t hb = (size_t)(b * 8 + h);
    const u16* ub = U  + hb * 1048576 + (size_t)(qt * 64) * 1024;
    const u16* vb = Vt + hb * 65536;

    float rlh[4], rlx[4];
    #pragma unroll
    for (int r = 0; r < 4; ++r)
      rlh[r] = frcp(rsum[hb * 1024 + qt * 64 + wrow + r]) * 0.125f;
    #pragma unroll
    for (int i = 0; i < 4; ++i)
      rlx[i] = frcp(rsum[hb * 1024 + qt * 64 + rs * 16 + kg * 4 + i]);

    gl_lds16(ub + (size_t)ur * 1024 + uc * 8, stg2 + tid * 8);
    gl_lds16(vb + (size_t)ur * 1024 + uc * 8, stg2 + 8192 + tid * 8);
    __syncthreads();

    floatx4 cpv = Z4;
    for (int t = 0; t < 8; ++t){
      if (t < 7){
        const int nb = ((t + 1) & 1) * 16384;
        gl_lds16(ub + (size_t)ur * 1024 + (t + 1) * 128 + uc * 8, stg2 + nb + tid * 8);
        gl_lds16(vb + (size_t)ur * 1024 + (t + 1) * 128 + uc * 8, stg2 + nb + 8192 + tid * 8);
      }
      const u16* Ut  = stg2 + (t & 1) * 16384;
      const u16* Vts = Ut + 8192;
      #pragma unroll
      for (int r = 0; r < 4; ++r){
        const int row = wrow + r;
        u32 w = *(const u32*)&Ut[row * 128 + ((lane * 2) ^ ((row & 7) * 8))];
        racc[r][2 * t]     += __uint_as_float(w << 16) * rlh[r];
        racc[r][2 * t + 1] += __uint_as_float(w & 0xFFFF0000u) * rlh[r];
      }
      #pragma unroll
      for (int ks = 0; ks < 4; ++ks){
        short8 a  = *(const short8*)&Ut[a_r * 128 + ((ks * 32 + kg * 8) ^ ((a_r & 7) * 8))];
        short8 bv = *(const short8*)&Vts[cres * 128 + ((ks * 32 + kg * 8) ^ ((cres & 7) * 8))];
        cpv = MFMA16(a, bv, cpv);
      }
      __syncthreads();
    }
    #pragma unroll
    for (int i = 0; i < 4; ++i){
      const int g = qt * 64 + rs * 16 + kg * 4 + i;
      xa[((size_t)(b * 1024 + g)) * 512 + h * 64 + cres] = f2bf(cpv[i] * rlx[i]);
    }
  }

  #pragma unroll
  for (int r = 0; r < 4; ++r){
    const size_t rb = ((size_t)(b * 1024 + qt * 64 + wrow + r)) * 1024;
    #pragma unroll
    for (int j = 0; j < 8; ++j){
      float2 v = {racc[r][2 * j], racc[r][2 * j + 1]};
      *(float2*)&ratt[rb + j * 128 + lane * 2] = v;
    }
  }
}

// ---------------- final FC, 128x128 tile (R14-proven) ----------------
__global__ __launch_bounds__(256) void k_fc(
    const u16* __restrict__ xa, const u16* __restrict__ wt,
    const float* __restrict__ bias, float* __restrict__ out)
{
  __shared__ __align__(16) u16 Asf[128 * 64];
  __shared__ __align__(16) u16 Bsf[128 * 64];
  const int tid = threadIdx.x, lane = tid & 63, wid = tid >> 6;
  const int wm = wid >> 1, wn = wid & 1;
  const int m0 = blockIdx.x * 128, n0 = blockIdx.y * 128;
  const int arow = lane & 15, kg = lane >> 4;
  const int br = tid >> 3, bc = tid & 7;
  u16* const adst = Asf + wid * 512;
  u16* const bdst = Bsf + wid * 512;

  floatx4 acc[4][4];
  #pragma unroll
  for (int i = 0; i < 4; ++i)
    #pragma unroll
    for (int j = 0; j < 4; ++j) acc[i][j] = Z4;

  for (int k0 = 0; k0 < 512; k0 += 64){
    #pragma unroll
    for (int q = 0; q < 4; ++q){
      gl_lds16(xa + (size_t)(m0 + q * 32 + br) * 512 + k0 + ((bc ^ (br & 7)) * 8),
               adst + q * 2048);
      gl_lds16(wt + (size_t)(n0 + q * 32 + br) * 512 + k0 + ((bc ^ (br & 7)) * 8),
               bdst + q * 2048);
    }
    __syncthreads();
    #pragma unroll
    for (int kk = 0; kk < 2; ++kk){
      short8 af[4], bf[4];
      #pragma unroll
      for (int mm = 0; mm < 4; ++mm){
        int rr = wm * 64 + mm * 16 + arow;
        af[mm] = *(const short8*)&Asf[rr * 64 + ((kk * 32 + kg * 8) ^ ((rr & 7) * 8))];
      }
      #pragma unroll
      for (int nn = 0; nn < 4; ++nn){
        int rr = wn * 64 + nn * 16 + arow;
        bf[nn] = *(const short8*)&Bsf[rr * 64 + ((kk * 32 + kg * 8) ^ ((rr & 7) * 8))];
      }
      #pragma unroll
      for (int mm = 0; mm < 4; ++mm)
        #pragma unroll
        for (int nn = 0; nn < 4; ++nn)
          acc[mm][nn] = MFMA16(af[mm], bf[nn], acc[mm][nn]);
    }
    __syncthreads();
  }
  #pragma unroll
  for (int mm = 0; mm < 4; ++mm)
    #pragma unroll
    for (int nn = 0; nn < 4; ++nn){
      int j = n0 + wn * 64 + nn * 16 + arow;
      float bval = bias[j];
      #pragma unroll
      for (int i = 0; i < 4; ++i){
        int sg = m0 + wm * 64 + mm * 16 + kg * 4 + i;
        out[(size_t)sg * 512 + j] = acc[mm][nn][i] + bval;
      }
    }
}

extern "C" void kernel_launch(void* const* d_in, const int* in_sizes, int n_in,
                              void* d_out, int out_size, void* d_ws, size_t ws_size,
                              hipStream_t stream)
{
  const float* query = (const float*)d_in[0];
  const float* key   = (const float*)d_in[1];
  const float* value = (const float*)d_in[2];
  const int*   mask  = (const int*)d_in[3];
  const float* wq  = (const float*)d_in[4];  const float* bq  = (const float*)d_in[5];
  const float* wk  = (const float*)d_in[6];  const float* bk  = (const float*)d_in[7];
  const float* wv  = (const float*)d_in[8];  const float* bv  = (const float*)d_in[9];
  const float* wq1 = (const float*)d_in[10]; const float* bq1 = (const float*)d_in[11];
  const float* wk1 = (const float*)d_in[12]; const float* bk1 = (const float*)d_in[13];
  const float* wfc = (const float*)d_in[14]; const float* bfc = (const float*)d_in[15];

  u16* ws  = (u16*)d_ws;
  u16* Qh  = ws;
  u16* Kh  = Qh  + 8388608;
  u16* Vt  = Kh  + 8388608;
  u16* Q1h = Vt  + 8388608;
  u16* K1h = Q1h + 8388608;
  u16* xa  = K1h + 8388608;
  u16* wts = xa  + 8388608;           // 6 * 262144 u16
  u16* U   = wts + 6 * 262144;        // 134217728 u16 = 268 MB
  float* rsum = (float*)(U + 134217728);  // 131072 f32
  u16* xb  = U;                       // bf16 x (3 x 8388608 u16 = 50 MB), aliased over
                                      // U: written by k_xcvt, read by k_proj, dead
                                      // before k_qk writes U.

  float* outx = (float*)d_out;
  float* ratt = outx + 8388608;

  k_wt6<<<dim3(8, 8, 6), dim3(256), 0, stream>>>(wq, wk, wv, wq1, wk1, wfc, wts);

  k_xcvt<<<dim3(4096, 3), dim3(256), 0, stream>>>(query, key, value, xb);

  k_proj<<<dim3(128, 4, 5), dim3(256), 0, stream>>>(
      xb, wts, bq, bk, bv, bq1, bk1, Qh, Kh, Vt, Q1h, K1h);

  (void)hipFuncSetAttribute((const void*)k_pvr,
                            hipFuncAttributeMaxDynamicSharedMemorySize, 65536);
  k_qk<<<dim3(16, 8, 4), dim3(1024), 0, stream>>>(
      Qh, Kh, Q1h, K1h, mask, U, rsum);
  k_pvr<<<dim3(16, 16), dim3(1024), 65536, stream>>>(
      U, rsum, Vt, xa, ratt);

  k_fc<<<dim3(128, 4), dim3(256), 0, stream>>>(
      xa, wts + 5 * 262144, bfc, outx);
}